// Round 1
// baseline (289.794 us; speedup 1.0000x reference)
//
#include <hip/hip_runtime.h>
#include <hip/hip_bf16.h>

// ---------- constants (problem is fully static) ----------
#define NQ  13294
#define NV  13294
#define BQ  26588          // B * NQ
#define CC  256
#define KK  256

typedef __attribute__((ext_vector_type(8))) short short8;
typedef __attribute__((ext_vector_type(4))) float f32x4;

static __device__ __forceinline__ float bf2f(ushort u) {
    unsigned int x = ((unsigned int)u) << 16;
    return __uint_as_float(x);
}
static __device__ __forceinline__ ushort f2bf(float f) {
    unsigned int x = __float_as_uint(f);
    unsigned int r = (x + 0x7fffu + ((x >> 16) & 1u)) >> 16;
    return (ushort)r;
}

// ---------- fp32 -> bf16 convert (vectorized) ----------
__global__ __launch_bounds__(256) void cvt_f32_bf16(const float* __restrict__ in,
                                                    ushort* __restrict__ out, int n) {
    int i = (blockIdx.x * 256 + threadIdx.x) * 4;
    if (i < n) {
        float4 v = *reinterpret_cast<const float4*>(in + i);
        ushort4 o;
        o.x = f2bf(v.x); o.y = f2bf(v.y); o.z = f2bf(v.z); o.w = f2bf(v.w);
        *reinterpret_cast<ushort4*>(out + i) = o;
    }
}

// ---------- weight prep: transpose to [N][K] bf16, concat biases ----------
__global__ __launch_bounds__(256) void prep_weights(
    const float* __restrict__ Wv, const float* __restrict__ Wo,
    const float* __restrict__ Wa, const float* __restrict__ Wu,
    const float* __restrict__ bo, const float* __restrict__ ba,
    ushort* __restrict__ tWv, ushort* __restrict__ tWoa,
    ushort* __restrict__ tWu, float* __restrict__ boa) {
    int i = blockIdx.x * 256 + threadIdx.x;
    if (i < 65536) {                       // W_val^T [256][256]
        int n = i >> 8, k = i & 255;
        tWv[i] = f2bf(Wv[k * 256 + n]);
    } else if (i < 65536 + 98304) {        // [W_off | W_attn]^T [384][256]
        int j = i - 65536;
        int n = j >> 8, k = j & 255;
        tWoa[j] = f2bf(n < 256 ? Wo[k * 256 + n] : Wa[k * 128 + (n - 256)]);
    } else if (i < 229376) {               // W_out^T [256][256]
        int j = i - 163840;
        int n = j >> 8, k = j & 255;
        tWu[j] = f2bf(Wu[k * 256 + n]);
    } else if (i < 229760) {               // bias concat [384]
        int j = i - 229376;
        boa[j] = j < 256 ? bo[j] : ba[j - 256];
    }
}

// ---------- bf16 MFMA GEMM: C[M,N] = A[M,256] * Bt[N,256]^T + bias ----------
// Tile 128x128, 4 waves (2x2), each wave 64x64 = 4x4 fragments of 16x16x32.
#define BM 128
#define BN 128
#define BK 32
#define LDP 40   // padded LDS row (bf16 elems): 80B stride -> modest bank spread

__global__ __launch_bounds__(256) void gemm_bf16(
    const ushort* __restrict__ A, const ushort* __restrict__ Bt,
    const float* __restrict__ bias, void* __restrict__ Cout,
    int M, int N, int out_bf16) {
    __shared__ ushort sA[BM * LDP];
    __shared__ ushort sB[BN * LDP];
    const int tid = threadIdx.x;
    const int wid = tid >> 6;
    const int lane = tid & 63;
    const int row0 = blockIdx.x * BM;
    const int col0 = blockIdx.y * BN;
    const int wr = (wid >> 1) * 64;
    const int wc = (wid & 1) * 64;

    f32x4 acc[4][4];
#pragma unroll
    for (int m = 0; m < 4; ++m)
#pragma unroll
        for (int n = 0; n < 4; ++n) acc[m][n] = (f32x4){0.f, 0.f, 0.f, 0.f};

    for (int kk = 0; kk < KK; kk += BK) {
        __syncthreads();
#pragma unroll
        for (int it = 0; it < 2; ++it) {
            int chunk = tid + it * 256;       // 0..511
            int r = chunk >> 2;               // 0..127
            int seg = chunk & 3;              // 16B segment within 64B row
            int gr = row0 + r; gr = gr < M ? gr : M - 1;
            uint4 va = *reinterpret_cast<const uint4*>(A + (size_t)gr * KK + kk + seg * 8);
            *reinterpret_cast<uint4*>(&sA[r * LDP + seg * 8]) = va;
            int gc = col0 + r;                // N is a multiple of 128
            uint4 vb = *reinterpret_cast<const uint4*>(Bt + (size_t)gc * KK + kk + seg * 8);
            *reinterpret_cast<uint4*>(&sB[r * LDP + seg * 8]) = vb;
        }
        __syncthreads();

        short8 a[4], b[4];
#pragma unroll
        for (int m = 0; m < 4; ++m)
            a[m] = *reinterpret_cast<const short8*>(&sA[(wr + m * 16 + (lane & 15)) * LDP + (lane >> 4) * 8]);
#pragma unroll
        for (int n = 0; n < 4; ++n)
            b[n] = *reinterpret_cast<const short8*>(&sB[(wc + n * 16 + (lane & 15)) * LDP + (lane >> 4) * 8]);
#pragma unroll
        for (int m = 0; m < 4; ++m)
#pragma unroll
            for (int n = 0; n < 4; ++n)
                acc[m][n] = __builtin_amdgcn_mfma_f32_16x16x32_bf16(a[m], b[n], acc[m][n], 0, 0, 0);
    }

    // epilogue: lane holds C[row=(lane>>4)*4+j][col=lane&15] per fragment
    const int lr = (lane >> 4) * 4;
    const int lc = lane & 15;
#pragma unroll
    for (int m = 0; m < 4; ++m) {
#pragma unroll
        for (int n = 0; n < 4; ++n) {
            int gcol = col0 + wc + n * 16 + lc;
            float bv = bias ? bias[gcol] : 0.f;
#pragma unroll
            for (int j = 0; j < 4; ++j) {
                int grow = row0 + wr + m * 16 + lr + j;
                if (grow < M) {
                    float v = acc[m][n][j] + bv;
                    if (out_bf16)
                        ((ushort*)Cout)[(size_t)grow * N + gcol] = f2bf(v);
                    else
                        ((float*)Cout)[(size_t)grow * N + gcol] = v;
                }
            }
        }
    }
}

// ---------- softmax + bilinear sampling + head-weighted accumulation ----------
// One block per (b,q). 256 threads = 8 heads x 32 channels.
__global__ __launch_bounds__(256) void msda_sample(
    const float* __restrict__ offattn,   // [BQ, 384] : 256 offsets + 128 logits
    const float* __restrict__ refp,      // [B, NQ, 4, 2]
    const ushort* __restrict__ v,        // bf16 [B, NV, 256] (col = h*32+d)
    ushort* __restrict__ out_acc) {      // bf16 [BQ, 256]
    __shared__ float s_off[256];
    __shared__ float s_log[128];
    __shared__ float s_m[8], s_inv[8];
    __shared__ int   s_idx[128][4];
    __shared__ float s_w[128][4];

    const int bq = blockIdx.x;
    const int b = bq / NQ;
    const int q = bq - b * NQ;
    const int tid = threadIdx.x;

    const float* oa = offattn + (size_t)bq * 384;
    s_off[tid] = oa[tid];
    if (tid < 128) s_log[tid] = oa[256 + tid];
    __syncthreads();

    if (tid < 8) {
        float m = -1e30f;
#pragma unroll
        for (int i = 0; i < 16; ++i) m = fmaxf(m, s_log[tid * 16 + i]);
        float s = 0.f;
#pragma unroll
        for (int i = 0; i < 16; ++i) s += __expf(s_log[tid * 16 + i] - m);
        s_m[tid] = m;
        s_inv[tid] = 1.f / s;
    }
    __syncthreads();

    if (tid < 128) {
        const int t = tid;
        const int h = t >> 4;
        const int l = (t >> 2) & 3;
        const int HW[4] = {100, 50, 25, 13};
        const int ST[4] = {0, 10000, 12500, 13125};
        const int W = HW[l], H = HW[l], st = ST[l];

        float wgt = __expf(s_log[t] - s_m[h]) * s_inv[h];
        float refx = refp[(((size_t)b * NQ + q) * 4 + l) * 2 + 0];
        float refy = refp[(((size_t)b * NQ + q) * 4 + l) * 2 + 1];
        float locx = refx + s_off[2 * t] / (float)W;
        float locy = refy + s_off[2 * t + 1] / (float)H;
        float x = locx * (float)W - 0.5f;
        float y = locy * (float)H - 0.5f;
        float x0f = floorf(x), y0f = floorf(y);
        float fx = x - x0f, fy = y - y0f;
        int x0 = (int)x0f, y0 = (int)y0f;
        float wx[2] = {1.f - fx, fx};
        float wy[2] = {1.f - fy, fy};
#pragma unroll
        for (int c = 0; c < 4; ++c) {
            int dx = c & 1, dy = c >> 1;
            int xi = x0 + dx, yi = y0 + dy;
            bool valid = (xi >= 0) & (xi < W) & (yi >= 0) & (yi < H);
            int cx = min(max(xi, 0), W - 1);
            int cy = min(max(yi, 0), H - 1);
            s_idx[t][c] = st + cy * W + cx;
            s_w[t][c] = valid ? wgt * wx[dx] * wy[dy] : 0.f;
        }
    }
    __syncthreads();

    const int h = tid >> 5;
    const int d = tid & 31;
    const ushort* vb = v + (size_t)b * NV * 256 + h * 32 + d;
    float acc = 0.f;
#pragma unroll
    for (int s = 0; s < 16; ++s) {
        int t = h * 16 + s;
#pragma unroll
        for (int c = 0; c < 4; ++c) {
            int pix = s_idx[t][c];
            float w = s_w[t][c];
            acc += w * bf2f(vb[(size_t)pix * 256]);
        }
    }
    out_acc[(size_t)bq * 256 + tid] = f2bf(acc);
}

// ---------- launch ----------
extern "C" void kernel_launch(void* const* d_in, const int* in_sizes, int n_in,
                              void* d_out, int out_size, void* d_ws, size_t ws_size,
                              hipStream_t stream) {
    const float* query  = (const float*)d_in[0];
    const float* value  = (const float*)d_in[1];
    const float* refp   = (const float*)d_in[2];
    const float* W_off  = (const float*)d_in[5];
    const float* b_off  = (const float*)d_in[6];
    const float* W_attn = (const float*)d_in[7];
    const float* b_attn = (const float*)d_in[8];
    const float* W_val  = (const float*)d_in[9];
    const float* b_val  = (const float*)d_in[10];
    const float* W_out  = (const float*)d_in[11];
    const float* b_out  = (const float*)d_in[12];

    const size_t ROWB = (size_t)BQ * 256 * 2;   // 13,613,056 B per bf16 [BQ,256] buffer
    char* ws = (char*)d_ws;
    ushort* q_bf    = (ushort*)(ws);
    ushort* v_bf    = (ushort*)(ws + ROWB);
    ushort* vproj   = (ushort*)(ws + 2 * ROWB);
    ushort* outacc  = (ushort*)(ws + 3 * ROWB);
    float*  offattn = (float*)(ws + 4 * ROWB);                       // [BQ,384] fp32
    char*   wbase   = ws + 4 * ROWB + (size_t)BQ * 384 * 4;
    ushort* tWv  = (ushort*)(wbase);
    ushort* tWoa = tWv + 65536;
    ushort* tWu  = tWoa + 98304;
    float*  boa  = (float*)(tWu + 65536);

    const int n = BQ * 256;                      // 6,806,528
    cvt_f32_bf16<<<(n / 4 + 255) / 256, 256, 0, stream>>>(query, q_bf, n);
    cvt_f32_bf16<<<(n / 4 + 255) / 256, 256, 0, stream>>>(value, v_bf, n);
    prep_weights<<<(229760 + 255) / 256, 256, 0, stream>>>(
        W_val, W_off, W_attn, W_out, b_off, b_attn, tWv, tWoa, tWu, boa);

    dim3 g1((BQ + BM - 1) / BM, 2);
    gemm_bf16<<<g1, 256, 0, stream>>>(v_bf, tWv, b_val, (void*)vproj, BQ, 256, 1);
    dim3 g2((BQ + BM - 1) / BM, 3);
    gemm_bf16<<<g2, 256, 0, stream>>>(q_bf, tWoa, boa, (void*)offattn, BQ, 384, 0);

    msda_sample<<<BQ, 256, 0, stream>>>(offattn, refp, vproj, outacc);

    dim3 g3((BQ + BM - 1) / BM, 2);
    gemm_bf16<<<g3, 256, 0, stream>>>(outacc, tWu, b_out, d_out, BQ, 256, 0);
}

// Round 2
// 135.506 us; speedup vs baseline: 2.1386x; 2.1386x over previous
//
#include <hip/hip_runtime.h>
#include <hip/hip_bf16.h>

// ---------- constants (problem is fully static) ----------
#define NQ  13294
#define NV  13294
#define BQ  26588          // B * NQ
#define KK  256

typedef __attribute__((ext_vector_type(8))) short short8;
typedef __attribute__((ext_vector_type(4))) float f32x4;

static __device__ __forceinline__ ushort f2bf(float f) {
    unsigned int x = __float_as_uint(f);
    unsigned int r = (x + 0x7fffu + ((x >> 16) & 1u)) >> 16;
    return (ushort)r;
}

// ---------- weight prep: transpose to [N][K] bf16, concat biases ----------
__global__ __launch_bounds__(256) void prep_weights(
    const float* __restrict__ Wv, const float* __restrict__ Wo,
    const float* __restrict__ Wa, const float* __restrict__ Wu,
    const float* __restrict__ bo, const float* __restrict__ ba,
    ushort* __restrict__ tWv, ushort* __restrict__ tWoa,
    ushort* __restrict__ tWu, float* __restrict__ boa) {
    int i = blockIdx.x * 256 + threadIdx.x;
    if (i < 65536) {                       // W_val^T [256][256]
        int n = i >> 8, k = i & 255;
        tWv[i] = f2bf(Wv[k * 256 + n]);
    } else if (i < 65536 + 98304) {        // [W_off | W_attn]^T [384][256]
        int j = i - 65536;
        int n = j >> 8, k = j & 255;
        tWoa[j] = f2bf(n < 256 ? Wo[k * 256 + n] : Wa[k * 128 + (n - 256)]);
    } else if (i < 229376) {               // W_out^T [256][256]
        int j = i - 163840;
        int n = j >> 8, k = j & 255;
        tWu[j] = f2bf(Wu[k * 256 + n]);
    } else if (i < 229760) {               // bias concat [384]
        int j = i - 229376;
        boa[j] = j < 256 ? bo[j] : ba[j - 256];
    }
}

// ---------- bf16 MFMA GEMM: C[M,N] = A[M,256] * Bt[N,256]^T + bias ----------
// Tile 128x128, 4 waves (2x2), each wave 64x64 = 4x4 fragments of 16x16x32.
// AF32: A is fp32 in global, converted to bf16 during LDS staging (fuses cvt).
#define BM 128
#define BN 128
#define BK 32
#define LDP 40   // padded LDS row (bf16 elems)

template<int AF32>
__global__ __launch_bounds__(256) void gemm_bf16(
    const void* __restrict__ Aptr, const ushort* __restrict__ Bt,
    const float* __restrict__ bias, void* __restrict__ Cout,
    int M, int N, int out_bf16) {
    __shared__ ushort sA[BM * LDP];
    __shared__ ushort sB[BN * LDP];
    const int tid = threadIdx.x;
    const int wid = tid >> 6;
    const int lane = tid & 63;
    const int row0 = blockIdx.x * BM;
    const int col0 = blockIdx.y * BN;
    const int wr = (wid >> 1) * 64;
    const int wc = (wid & 1) * 64;

    f32x4 acc[4][4];
#pragma unroll
    for (int m = 0; m < 4; ++m)
#pragma unroll
        for (int n = 0; n < 4; ++n) acc[m][n] = (f32x4){0.f, 0.f, 0.f, 0.f};

    for (int kk = 0; kk < KK; kk += BK) {
        __syncthreads();
#pragma unroll
        for (int it = 0; it < 2; ++it) {
            int chunk = tid + it * 256;       // 0..511
            int r = chunk >> 2;               // 0..127
            int seg = chunk & 3;              // 8-channel segment
            int gr = row0 + r; gr = gr < M ? gr : M - 1;
            uint4 wa;
            if (AF32) {
                const float* Af = (const float*)Aptr + (size_t)gr * KK + kk + seg * 8;
                float4 f0 = *reinterpret_cast<const float4*>(Af);
                float4 f1 = *reinterpret_cast<const float4*>(Af + 4);
                wa.x = (uint)f2bf(f0.x) | ((uint)f2bf(f0.y) << 16);
                wa.y = (uint)f2bf(f0.z) | ((uint)f2bf(f0.w) << 16);
                wa.z = (uint)f2bf(f1.x) | ((uint)f2bf(f1.y) << 16);
                wa.w = (uint)f2bf(f1.z) | ((uint)f2bf(f1.w) << 16);
            } else {
                wa = *reinterpret_cast<const uint4*>((const ushort*)Aptr + (size_t)gr * KK + kk + seg * 8);
            }
            *reinterpret_cast<uint4*>(&sA[r * LDP + seg * 8]) = wa;
            int gc = col0 + r;                // N is a multiple of 128
            uint4 vb4 = *reinterpret_cast<const uint4*>(Bt + (size_t)gc * KK + kk + seg * 8);
            *reinterpret_cast<uint4*>(&sB[r * LDP + seg * 8]) = vb4;
        }
        __syncthreads();

        short8 a[4], b[4];
#pragma unroll
        for (int m = 0; m < 4; ++m)
            a[m] = *reinterpret_cast<const short8*>(&sA[(wr + m * 16 + (lane & 15)) * LDP + (lane >> 4) * 8]);
#pragma unroll
        for (int n = 0; n < 4; ++n)
            b[n] = *reinterpret_cast<const short8*>(&sB[(wc + n * 16 + (lane & 15)) * LDP + (lane >> 4) * 8]);
#pragma unroll
        for (int m = 0; m < 4; ++m)
#pragma unroll
            for (int n = 0; n < 4; ++n)
                acc[m][n] = __builtin_amdgcn_mfma_f32_16x16x32_bf16(a[m], b[n], acc[m][n], 0, 0, 0);
    }

    const int lr = (lane >> 4) * 4;
    const int lc = lane & 15;
#pragma unroll
    for (int m = 0; m < 4; ++m) {
#pragma unroll
        for (int n = 0; n < 4; ++n) {
            int gcol = col0 + wc + n * 16 + lc;
            float bv = bias ? bias[gcol] : 0.f;
#pragma unroll
            for (int j = 0; j < 4; ++j) {
                int grow = row0 + wr + m * 16 + lr + j;
                if (grow < M) {
                    float v = acc[m][n][j] + bv;
                    if (out_bf16)
                        ((ushort*)Cout)[(size_t)grow * N + gcol] = f2bf(v);
                    else
                        ((float*)Cout)[(size_t)grow * N + gcol] = v;
                }
            }
        }
    }
}

// ---------- softmax + bilinear sampling + head-weighted accumulation ----------
// One WAVE per (b,q); 4 queries per block. Lane = h*8 + s2*4 + d4.
// Gathers are 16B uint4 (8 channels); LDS (idx,w) table laid out conflict-free.
__global__ __launch_bounds__(256) void msda_sample(
    const float* __restrict__ offattn,   // [BQ, 384] : 256 offsets + 128 logits
    const float* __restrict__ refp,      // [B, NQ, 4, 2]
    const ushort* __restrict__ v,        // bf16 [B, NV, 256] (col = h*32+d)
    ushort* __restrict__ out_acc) {      // bf16 [BQ, 256]
    // layout [qi][c][u] : per-(ss,c) b64 read across 64 lanes hits u = ss*16 + (0..15)
    // consecutive -> banks (2u, 2u+1) mod 32 cover all 32 banks once. Conflict-free.
    __shared__ int2 s_iw[4][4][128];

    const int tid = threadIdx.x;
    const int qi = tid >> 6;
    const int lane = tid & 63;
    const int bq = blockIdx.x * 4 + qi;          // 26588 = 4 * 6647 exact
    const int b = bq / NQ;
    const int q = bq - b * NQ;

    // ---- prep: each lane owns table entries t0=2*lane, t0+1 ----
    const float* oa = offattn + (size_t)bq * 384;
    const int t0 = lane * 2;
    float2 lg = *reinterpret_cast<const float2*>(oa + 256 + t0);
    float m = fmaxf(lg.x, lg.y);
    m = fmaxf(m, __shfl_xor(m, 1));
    m = fmaxf(m, __shfl_xor(m, 2));
    m = fmaxf(m, __shfl_xor(m, 4));              // max over the head's 16 logits
    float e0 = __expf(lg.x - m), e1 = __expf(lg.y - m);
    float ssum = e0 + e1;
    ssum += __shfl_xor(ssum, 1);
    ssum += __shfl_xor(ssum, 2);
    ssum += __shfl_xor(ssum, 4);
    float inv = 1.f / ssum;

    float4 off4 = *reinterpret_cast<const float4*>(oa + 2 * t0);  // (ox0,oy0,ox1,oy1)
    const int l = (t0 >> 2) & 3;                 // same level for t0 and t0+1
    const int   Wi = (l == 0) ? 100 : (l == 1) ? 50 : (l == 2) ? 25 : 13;
    const int   st = (l == 0) ? 0 : (l == 1) ? 10000 : (l == 2) ? 12500 : 13125;
    const float Wf = (float)Wi;
    float rx = refp[(((size_t)b * NQ + q) * 4 + l) * 2 + 0];
    float ry = refp[(((size_t)b * NQ + q) * 4 + l) * 2 + 1];

#pragma unroll
    for (int j = 0; j < 2; ++j) {
        int t = t0 + j;
        float e = (j ? e1 : e0) * inv;
        float ox = j ? off4.z : off4.x;
        float oy = j ? off4.w : off4.y;
        float x = fmaf(rx, Wf, ox) - 0.5f;       // == (rx + ox/W)*W - 0.5
        float y = fmaf(ry, Wf, oy) - 0.5f;
        float x0f = floorf(x), y0f = floorf(y);
        float fx = x - x0f, fy = y - y0f;
        int x0 = (int)x0f, y0 = (int)y0f;
        float wx[2] = {1.f - fx, fx}, wy[2] = {1.f - fy, fy};
        int u = ((t & 7) << 4) | (t >> 3);       // bit-swizzled storage index
#pragma unroll
        for (int c = 0; c < 4; ++c) {
            int dx = c & 1, dy = c >> 1;
            int xi = x0 + dx, yi = y0 + dy;
            bool valid = (xi >= 0) & (xi < Wi) & (yi >= 0) & (yi < Wi);
            int cx = min(max(xi, 0), Wi - 1);
            int cy = min(max(yi, 0), Wi - 1);
            int2 iw;
            iw.x = st + cy * Wi + cx;
            iw.y = __float_as_int(valid ? e * wx[dx] * wy[dy] : 0.f);
            s_iw[qi][c][u] = iw;
        }
    }
    __syncthreads();

    // ---- gather: lane (h, s2, d4) accumulates 8 channels over 8 samples ----
    const int h  = lane >> 3;
    const int s2 = (lane >> 2) & 1;
    const int d4 = lane & 3;
    const ushort* vb = v + (size_t)b * NV * 256 + h * 32 + d4 * 8;
    float acc[8] = {0.f, 0.f, 0.f, 0.f, 0.f, 0.f, 0.f, 0.f};
#pragma unroll
    for (int ss = 0; ss < 8; ++ss) {
        int uu = (ss << 4) + h * 2 + s2;
#pragma unroll
        for (int c = 0; c < 4; ++c) {
            int2 iw = s_iw[qi][c][uu];
            float w = __int_as_float(iw.y);
            uint4 u4 = *reinterpret_cast<const uint4*>(vb + (size_t)iw.x * 256);
            acc[0] = fmaf(__uint_as_float(u4.x << 16), w, acc[0]);
            acc[1] = fmaf(__uint_as_float(u4.x & 0xffff0000u), w, acc[1]);
            acc[2] = fmaf(__uint_as_float(u4.y << 16), w, acc[2]);
            acc[3] = fmaf(__uint_as_float(u4.y & 0xffff0000u), w, acc[3]);
            acc[4] = fmaf(__uint_as_float(u4.z << 16), w, acc[4]);
            acc[5] = fmaf(__uint_as_float(u4.z & 0xffff0000u), w, acc[5]);
            acc[6] = fmaf(__uint_as_float(u4.w << 16), w, acc[6]);
            acc[7] = fmaf(__uint_as_float(u4.w & 0xffff0000u), w, acc[7]);
        }
    }
#pragma unroll
    for (int i = 0; i < 8; ++i) acc[i] += __shfl_xor(acc[i], 4);   // reduce over s2
    if (s2 == 0) {
        uint4 o;
        o.x = (uint)f2bf(acc[0]) | ((uint)f2bf(acc[1]) << 16);
        o.y = (uint)f2bf(acc[2]) | ((uint)f2bf(acc[3]) << 16);
        o.z = (uint)f2bf(acc[4]) | ((uint)f2bf(acc[5]) << 16);
        o.w = (uint)f2bf(acc[6]) | ((uint)f2bf(acc[7]) << 16);
        *reinterpret_cast<uint4*>(out_acc + (size_t)bq * 256 + h * 32 + d4 * 8) = o;
    }
}

// ---------- launch ----------
extern "C" void kernel_launch(void* const* d_in, const int* in_sizes, int n_in,
                              void* d_out, int out_size, void* d_ws, size_t ws_size,
                              hipStream_t stream) {
    const float* query  = (const float*)d_in[0];
    const float* value  = (const float*)d_in[1];
    const float* refp   = (const float*)d_in[2];
    const float* W_off  = (const float*)d_in[5];
    const float* b_off  = (const float*)d_in[6];
    const float* W_attn = (const float*)d_in[7];
    const float* b_attn = (const float*)d_in[8];
    const float* W_val  = (const float*)d_in[9];
    const float* b_val  = (const float*)d_in[10];
    const float* W_out  = (const float*)d_in[11];
    const float* b_out  = (const float*)d_in[12];

    const size_t ROWB = (size_t)BQ * 256 * 2;   // bytes of one bf16 [BQ,256] buffer
    char* ws = (char*)d_ws;
    ushort* vproj   = (ushort*)(ws);
    ushort* outacc  = (ushort*)(ws + ROWB);
    float*  offattn = (float*)(ws + 2 * ROWB);                    // [BQ,384] fp32
    char*   wbase   = ws + 2 * ROWB + (size_t)BQ * 384 * 4;
    ushort* tWv  = (ushort*)(wbase);
    ushort* tWoa = tWv + 65536;
    ushort* tWu  = tWoa + 98304;
    float*  boa  = (float*)(tWu + 65536);

    prep_weights<<<(229760 + 255) / 256, 256, 0, stream>>>(
        W_val, W_off, W_attn, W_out, b_off, b_attn, tWv, tWoa, tWu, boa);

    dim3 g1((BQ + BM - 1) / BM, 2);
    gemm_bf16<1><<<g1, 256, 0, stream>>>(value, tWv, b_val, (void*)vproj, BQ, 256, 1);
    dim3 g2((BQ + BM - 1) / BM, 3);
    gemm_bf16<1><<<g2, 256, 0, stream>>>(query, tWoa, boa, (void*)offattn, BQ, 384, 0);

    msda_sample<<<BQ / 4, 256, 0, stream>>>(offattn, refp, vproj, outacc);

    dim3 g3((BQ + BM - 1) / BM, 2);
    gemm_bf16<0><<<g3, 256, 0, stream>>>(outacc, tWu, b_out, d_out, BQ, 256, 0);
}